// Round 22
// baseline (443.911 us; speedup 1.0000x reference)
//
#include <hip/hip_runtime.h>

#define HDIM 64

typedef _Float16 h2  __attribute__((ext_vector_type(2)));   // dot2 operand type
typedef __fp16   fp2 __attribute__((ext_vector_type(2)));   // cvt_pkrtz result type

#if defined(__has_builtin)
# if __has_builtin(__builtin_amdgcn_fdot2)
#  define FDOT2(a, b, c) __builtin_amdgcn_fdot2((a), (b), (c), false)
# endif
#endif
#ifndef FDOT2
__device__ __forceinline__ float fdot2_asm(h2 a, h2 b, float c) {
    float d;
    asm("v_dot2_f32_f16 %0, %1, %2, %3" : "=v"(d) : "v"(a), "v"(b), "v"(c));
    return d;
}
# define FDOT2(a, b, c) fdot2_asm((a), (b), (c))
#endif

__device__ __forceinline__ float fast_sigmoid(float v) {
    return __builtin_amdgcn_rcpf(1.0f + __builtin_amdgcn_exp2f(-1.442695041f * v));
}

__device__ __forceinline__ float fast_tanh(float v) {
    return 1.0f - 2.0f * __builtin_amdgcn_rcpf(1.0f + __builtin_amdgcn_exp2f(2.885390082f * v));
}

// GATE-PAIR SPLIT, f16 (round-20 champion + critical-path micro-tune):
// 512 blocks x 128 threads (2 waves) = 1024 waves = 1/SIMD.
// Wave 0: lane l owns gate rows {l, 64+l} (i,f) of unit l, full K=64 dots.
// Wave 1: lane l owns gate rows {128+l, 192+l} (g,o).
// 128 f16 weights = 64 packed uints/lane, pinned.
// r22 tweaks vs r20: (1) bias + x·w seeded into the dot-chain HEADS (xt's
// LDS read is h-independent, hoistable a step early) — removes ~4 dependent
// ops from the post-dot tail; (2) gate exchange split into two b32 writes so
// s0's ds_write issues while s1's transcendental is still in flight.
// h broadcast: cvt_pkrtz + DPP quad_perm + 32 readlane (r19-validated).
// x staged via LDS in 64-step chunks (r6-validated).
__global__ __launch_bounds__(128)
__attribute__((amdgpu_waves_per_eu(1, 1)))
void bilstm_kernel(const float* __restrict__ x,
                   const float* __restrict__ w_ih_f,
                   const float* __restrict__ w_hh_f,
                   const float* __restrict__ b_ih_f,
                   const float* __restrict__ b_hh_f,
                   const float* __restrict__ w_ih_b,
                   const float* __restrict__ b_ih_b,
                   const float* __restrict__ b_hh_b,
                   const float* __restrict__ w_fc,
                   const float* __restrict__ b_fc,
                   float* __restrict__ out,
                   int T)
{
    const int b   = blockIdx.x;
    const int tid = threadIdx.x;
    const int w   = tid >> 6;      // 0: gates {i,f}, 1: gates {g,o}
    const int l   = tid & 63;      // unit index

    __shared__ __align__(16) float gbuf[2][2][2][HDIM]; // [parity][wave][slot][unit]
    __shared__ __align__(16) float xstage[2][256];      // [parity][s*4+comp]

    // ---- pack 2 gate rows (K=64 each) into 64 h2 regs (stored as uint) ----
    const int r0 = (w << 7) | l;        // w0: row l (i) ; w1: row 128+l (g)
    const int r1 = r0 + 64;             // w0: row 64+l (f); w1: row 192+l (o)
    unsigned wu[64];                    // [g*32 + p] = packed {w[2p], w[2p+1]}
    #pragma unroll
    for (int g = 0; g < 2; ++g) {
        const float* row = w_hh_f + (size_t)(g ? r1 : r0) * HDIM;
        #pragma unroll
        for (int q = 0; q < 16; ++q) {
            float4 v = *(const float4*)(row + 4 * q);
            fp2 p0 = __builtin_amdgcn_cvt_pkrtz(v.x, v.y);
            fp2 p1 = __builtin_amdgcn_cvt_pkrtz(v.z, v.w);
            wu[(g << 5) + 2 * q + 0] = __builtin_bit_cast(unsigned, p0);
            wu[(g << 5) + 2 * q + 1] = __builtin_bit_cast(unsigned, p1);
        }
    }
    #pragma unroll
    for (int qq = 0; qq < 8; ++qq) {
        asm volatile("" : "+v"(wu[8*qq+0]), "+v"(wu[8*qq+1]),
                          "+v"(wu[8*qq+2]), "+v"(wu[8*qq+3]),
                          "+v"(wu[8*qq+4]), "+v"(wu[8*qq+5]),
                          "+v"(wu[8*qq+6]), "+v"(wu[8*qq+7]));
    }

    float4 wx0 = *(const float4*)(w_ih_f + (size_t)r0 * 4);
    float4 wx1 = *(const float4*)(w_ih_f + (size_t)r1 * 4);
    float  bz0 = b_ih_f[r0] + b_hh_f[r0];
    float  bz1 = b_ih_f[r1] + b_hh_f[r1];
    asm volatile("" : "+v"(wx0.x), "+v"(wx0.y), "+v"(wx0.z), "+v"(wx0.w), "+v"(bz0));
    asm volatile("" : "+v"(wx1.x), "+v"(wx1.y), "+v"(wx1.z), "+v"(wx1.w), "+v"(bz1));

    const float* xb = x + (size_t)b * T * 4;
    const int lim = T * 4 - 1;

    // prologue: stage chunk 0
    {
        int i0 = tid;        if (i0 > lim) i0 = lim;
        int i1 = tid + 128;  if (i1 > lim) i1 = lim;
        xstage[0][tid]       = xb[i0];
        xstage[0][tid + 128] = xb[i1];
    }
    __syncthreads();

    // h broadcast state: 32 packed f16 pairs (uniform after readlane)
    unsigned hs[32];
    #pragma unroll
    for (int k = 0; k < 32; ++k) hs[k] = 0u;
    float c = 0.0f, h = 0.0f;

    #define W2(g, pp) __builtin_bit_cast(h2, wu[((g) << 5) + (pp)])
    #define H2(u)     __builtin_bit_cast(h2, (u))

    const int NCH = (T + 63) >> 6;

    for (int ch = 0; ch < NCH; ++ch) {
        const int nst = ((T - (ch << 6)) < 64) ? (T - (ch << 6)) : 64;
        const float* xs = xstage[ch & 1];
        const bool more = (ch + 1 < NCH);
        float xn0 = 0.0f, xn1 = 0.0f;
        if (more) {
            int i0 = ((ch + 1) << 8) + tid;        if (i0 > lim) i0 = lim;
            int i1 = ((ch + 1) << 8) + tid + 128;  if (i1 > lim) i1 = lim;
            xn0 = xb[i0];
            xn1 = xb[i1];   // drained at first in-chunk barrier (once / 64 steps)
        }

        #define STEP(S, P) do {                                              \
            const float4 xt = *(const float4*)(&xs[(S) << 2]);               \
            /* seed chains with bias + x·w (h-independent, hoistable) */     \
            float a0A = fmaf(wx0.x, xt.x, bz0);                              \
            a0A = fmaf(wx0.y, xt.y, a0A);                                    \
            float a0B = wx0.z * xt.z;                                        \
            a0B = fmaf(wx0.w, xt.w, a0B);                                    \
            float a1A = fmaf(wx1.x, xt.x, bz1);                              \
            a1A = fmaf(wx1.y, xt.y, a1A);                                    \
            float a1B = wx1.z * xt.z;                                        \
            a1B = fmaf(wx1.w, xt.w, a1B);                                    \
            _Pragma("unroll")                                                \
            for (int q = 0; q < 8; ++q) {                                    \
                a0A = FDOT2(W2(0, 4*q+0), H2(hs[4*q+0]), a0A);               \
                a0B = FDOT2(W2(0, 4*q+1), H2(hs[4*q+1]), a0B);               \
                a0A = FDOT2(W2(0, 4*q+2), H2(hs[4*q+2]), a0A);               \
                a0B = FDOT2(W2(0, 4*q+3), H2(hs[4*q+3]), a0B);               \
                a1A = FDOT2(W2(1, 4*q+0), H2(hs[4*q+0]), a1A);               \
                a1B = FDOT2(W2(1, 4*q+1), H2(hs[4*q+1]), a1B);               \
                a1A = FDOT2(W2(1, 4*q+2), H2(hs[4*q+2]), a1A);               \
                a1B = FDOT2(W2(1, 4*q+3), H2(hs[4*q+3]), a1B);               \
            }                                                                \
            const float A0 = a0A + a0B;                                      \
            const float A1 = a1A + a1B;                                      \
            float s0, s1;                                                    \
            if (w == 0) { s0 = fast_sigmoid(A0); s1 = fast_sigmoid(A1); }    \
            else        { s0 = fast_tanh(A0);    s1 = fast_sigmoid(A1); }    \
            gbuf[P][w][0][l] = s0;     /* b32: issues as soon as s0 ready */ \
            gbuf[P][w][1][l] = s1;                                           \
            __syncthreads();                                                 \
            const float ovx = gbuf[P][w ^ 1][0][l];                          \
            const float ovy = gbuf[P][w ^ 1][1][l];                          \
            float gi, gf, gg, go;                                            \
            if (w == 0) { gi = s0; gf = s1; gg = ovx; go = ovy; }            \
            else        { gi = ovx; gf = ovy; gg = s0; go = s1; }            \
            c = gf * c + gi * gg;                                            \
            h = go * fast_tanh(c);                                           \
            const unsigned hr = __builtin_bit_cast(unsigned,                 \
                                    __builtin_amdgcn_cvt_pkrtz(h, h));       \
            const unsigned nb = (unsigned)__builtin_amdgcn_update_dpp(       \
                                    (int)hr, (int)hr, 0xB1, 0xF, 0xF, true); \
            const unsigned pk = (hr & 0xffffu) | (nb << 16);                 \
            _Pragma("unroll")                                                \
            for (int k = 0; k < 32; ++k)                                     \
                hs[k] = (unsigned)__builtin_amdgcn_readlane((int)pk, 2 * k); \
        } while (0)

        for (int s = 0; s < nst; s += 2) {
            STEP(s,     0);
            STEP(s + 1, 1);
        }
        #undef STEP

        if (more) {
            xstage[(ch + 1) & 1][tid]       = xn0;
            xstage[(ch + 1) & 1][tid + 128] = xn1;
            __syncthreads();
        }
    }

    #undef W2
    #undef H2

    // ---- epilogue: wave 0 — backward cell + fc + sigmoid ----
    if (w == 0) {
        // backward-direction single cell from zero state at x[:, T-1]
        // (w_hh_b never multiplies nonzero state)
        float4 xl = *(const float4*)(xb + 4 * (T - 1));
        float gb[4];
        #pragma unroll
        for (int g = 0; g < 4; ++g) {
            const int r = (g << 6) | l;
            float4 wb = *(const float4*)(w_ih_b + (size_t)r * 4);
            gb[g] = b_ih_b[r] + b_hh_b[r]
                  + wb.x * xl.x + wb.y * xl.y + wb.z * xl.z + wb.w * xl.w;
        }
        const float ib  = fast_sigmoid(gb[0]);
        const float ggb = fast_tanh(gb[2]);
        const float ob  = fast_sigmoid(gb[3]);
        const float cb  = ib * ggb;
        const float hbk = ob * fast_tanh(cb);

        // h register holds the final forward h for unit l (computed redundantly)
        float p = w_fc[l] * h + w_fc[HDIM + l] * hbk;
        #pragma unroll
        for (int off = 32; off; off >>= 1) p += __shfl_xor(p, off);

        if (l == 0) out[b] = fast_sigmoid(p + b_fc[0]);
    }
}

extern "C" void kernel_launch(void* const* d_in, const int* in_sizes, int n_in,
                              void* d_out, int out_size, void* d_ws, size_t ws_size,
                              hipStream_t stream) {
    const float* x      = (const float*)d_in[0];
    const float* w_ih_f = (const float*)d_in[1];
    const float* w_hh_f = (const float*)d_in[2];
    const float* b_ih_f = (const float*)d_in[3];
    const float* b_hh_f = (const float*)d_in[4];
    const float* w_ih_b = (const float*)d_in[5];
    // d_in[6] = w_hh_b — unused (backward cell starts from zero state)
    const float* b_ih_b = (const float*)d_in[7];
    const float* b_hh_b = (const float*)d_in[8];
    const float* w_fc   = (const float*)d_in[9];
    const float* b_fc   = (const float*)d_in[10];
    float* out = (float*)d_out;

    const int B = out_size;                 // 512
    const int T = in_sizes[0] / (B * 4);    // 1000

    bilstm_kernel<<<dim3(B), dim3(128), 0, stream>>>(
        x, w_ih_f, w_hh_f, b_ih_f, b_hh_f,
        w_ih_b, b_ih_b, b_hh_b, w_fc, b_fc, out, T);
}

// Round 23
// 405.290 us; speedup vs baseline: 1.0953x; 1.0953x over previous
//
#include <hip/hip_runtime.h>

#define HDIM 64

typedef _Float16 h2  __attribute__((ext_vector_type(2)));   // dot2 operand type
typedef __fp16   fp2 __attribute__((ext_vector_type(2)));   // cvt_pkrtz result type

#if defined(__has_builtin)
# if __has_builtin(__builtin_amdgcn_fdot2)
#  define FDOT2(a, b, c) __builtin_amdgcn_fdot2((a), (b), (c), false)
# endif
#endif
#ifndef FDOT2
__device__ __forceinline__ float fdot2_asm(h2 a, h2 b, float c) {
    float d;
    asm("v_dot2_f32_f16 %0, %1, %2, %3" : "=v"(d) : "v"(a), "v"(b), "v"(c));
    return d;
}
# define FDOT2(a, b, c) fdot2_asm((a), (b), (c))
#endif

__device__ __forceinline__ float fast_sigmoid(float v) {
    return __builtin_amdgcn_rcpf(1.0f + __builtin_amdgcn_exp2f(-1.442695041f * v));
}

__device__ __forceinline__ float fast_tanh(float v) {
    return 1.0f - 2.0f * __builtin_amdgcn_rcpf(1.0f + __builtin_amdgcn_exp2f(2.885390082f * v));
}

// GATE-PAIR SPLIT, f16 (round-20 champion, restored — best of 22 rounds):
// 512 blocks x 128 threads (2 waves) = 1024 waves = 1 wave/SIMD.
// Wave 0: lane l owns gate rows {l, 64+l}    (i, f) of unit l, full K=64 dots.
// Wave 1: lane l owns gate rows {128+l, 192+l} (g, o).
// 128 f16 weights = 64 packed uints/lane, pinned in VGPRs.
// Per step/wave: 64 dot2 + act pair + float2 LDS exchange + 1 barrier +
// redundant cell + in-register h broadcast (cvt_pkrtz + DPP quad_perm +
// 32 packed readlanes — no LDS round-trip for h).
// x staged via LDS in 64-step chunks (global loads drain once per chunk).
// IMPORTANT (r22 lesson): x·w is folded AFTER the dot loop — seeding it into
// the chain heads puts the xt LDS read on the critical path (465 vs 426 us).
// Design space bracketed over r6-r22: per-wave dots 128/64/32 -> 447/426/447;
// waves/elem 1/2/4; elems/wave 1/2; h via LDS/readlane; reduce shfl/permlane;
// barriers 2/1/0; f32/f16. This config is the measured optimum: latency-bound
// on the inherently serial T=1000 recurrence (HBM 0.13%, VALU-issue ~30%).
__global__ __launch_bounds__(128)
__attribute__((amdgpu_waves_per_eu(1, 1)))
void bilstm_kernel(const float* __restrict__ x,
                   const float* __restrict__ w_ih_f,
                   const float* __restrict__ w_hh_f,
                   const float* __restrict__ b_ih_f,
                   const float* __restrict__ b_hh_f,
                   const float* __restrict__ w_ih_b,
                   const float* __restrict__ b_ih_b,
                   const float* __restrict__ b_hh_b,
                   const float* __restrict__ w_fc,
                   const float* __restrict__ b_fc,
                   float* __restrict__ out,
                   int T)
{
    const int b   = blockIdx.x;
    const int tid = threadIdx.x;
    const int w   = tid >> 6;      // 0: gates {i,f}, 1: gates {g,o}
    const int l   = tid & 63;      // unit index

    __shared__ __align__(8)  float2 gbuf[2][2][HDIM];  // [parity][wave][unit]
    __shared__ __align__(16) float  xstage[2][256];    // [parity][s*4+comp]

    // ---- pack 2 gate rows (K=64 each) into 64 h2 regs (stored as uint) ----
    const int r0 = (w << 7) | l;        // w0: row l (i) ; w1: row 128+l (g)
    const int r1 = r0 + 64;             // w0: row 64+l (f); w1: row 192+l (o)
    unsigned wu[64];                    // [g*32 + p] = packed {w[2p], w[2p+1]}
    #pragma unroll
    for (int g = 0; g < 2; ++g) {
        const float* row = w_hh_f + (size_t)(g ? r1 : r0) * HDIM;
        #pragma unroll
        for (int q = 0; q < 16; ++q) {
            float4 v = *(const float4*)(row + 4 * q);
            fp2 p0 = __builtin_amdgcn_cvt_pkrtz(v.x, v.y);
            fp2 p1 = __builtin_amdgcn_cvt_pkrtz(v.z, v.w);
            wu[(g << 5) + 2 * q + 0] = __builtin_bit_cast(unsigned, p0);
            wu[(g << 5) + 2 * q + 1] = __builtin_bit_cast(unsigned, p1);
        }
    }
    #define PIN_WU()                                                        \
        _Pragma("unroll")                                                   \
        for (int qq = 0; qq < 8; ++qq) {                                    \
            asm volatile("" : "+v"(wu[8*qq+0]), "+v"(wu[8*qq+1]),           \
                              "+v"(wu[8*qq+2]), "+v"(wu[8*qq+3]),           \
                              "+v"(wu[8*qq+4]), "+v"(wu[8*qq+5]),           \
                              "+v"(wu[8*qq+6]), "+v"(wu[8*qq+7]));          \
        }
    PIN_WU()

    float4 wx0 = *(const float4*)(w_ih_f + (size_t)r0 * 4);
    float4 wx1 = *(const float4*)(w_ih_f + (size_t)r1 * 4);
    float  bz0 = b_ih_f[r0] + b_hh_f[r0];
    float  bz1 = b_ih_f[r1] + b_hh_f[r1];
    asm volatile("" : "+v"(wx0.x), "+v"(wx0.y), "+v"(wx0.z), "+v"(wx0.w), "+v"(bz0));
    asm volatile("" : "+v"(wx1.x), "+v"(wx1.y), "+v"(wx1.z), "+v"(wx1.w), "+v"(bz1));

    const float* xb = x + (size_t)b * T * 4;
    const int lim = T * 4 - 1;

    // prologue: stage chunk 0
    {
        int i0 = tid;        if (i0 > lim) i0 = lim;
        int i1 = tid + 128;  if (i1 > lim) i1 = lim;
        xstage[0][tid]       = xb[i0];
        xstage[0][tid + 128] = xb[i1];
    }
    __syncthreads();

    // h broadcast state: 32 packed f16 pairs (uniform after readlane)
    unsigned hs[32];
    #pragma unroll
    for (int k = 0; k < 32; ++k) hs[k] = 0u;
    float c = 0.0f, h = 0.0f;

    #define W2(g, pp) __builtin_bit_cast(h2, wu[((g) << 5) + (pp)])
    #define H2(u)     __builtin_bit_cast(h2, (u))

    const int NCH = (T + 63) >> 6;

    for (int ch = 0; ch < NCH; ++ch) {
        const int nst = ((T - (ch << 6)) < 64) ? (T - (ch << 6)) : 64;
        const float* xs = xstage[ch & 1];
        const bool more = (ch + 1 < NCH);
        float xn0 = 0.0f, xn1 = 0.0f;
        if (more) {
            int i0 = ((ch + 1) << 8) + tid;        if (i0 > lim) i0 = lim;
            int i1 = ((ch + 1) << 8) + tid + 128;  if (i1 > lim) i1 = lim;
            xn0 = xb[i0];
            xn1 = xb[i1];   // drained at first in-chunk barrier (once / 64 steps)
        }

        #define STEP(S, P) do {                                              \
            const float4 xt = *(const float4*)(&xs[(S) << 2]);               \
            float a0A = bz0, a0B = 0.0f, a1A = bz1, a1B = 0.0f;              \
            _Pragma("unroll")                                                \
            for (int q = 0; q < 8; ++q) {                                    \
                a0A = FDOT2(W2(0, 4*q+0), H2(hs[4*q+0]), a0A);               \
                a0B = FDOT2(W2(0, 4*q+1), H2(hs[4*q+1]), a0B);               \
                a0A = FDOT2(W2(0, 4*q+2), H2(hs[4*q+2]), a0A);               \
                a0B = FDOT2(W2(0, 4*q+3), H2(hs[4*q+3]), a0B);               \
                a1A = FDOT2(W2(1, 4*q+0), H2(hs[4*q+0]), a1A);               \
                a1B = FDOT2(W2(1, 4*q+1), H2(hs[4*q+1]), a1B);               \
                a1A = FDOT2(W2(1, 4*q+2), H2(hs[4*q+2]), a1A);               \
                a1B = FDOT2(W2(1, 4*q+3), H2(hs[4*q+3]), a1B);               \
            }                                                                \
            const float A0 = a0A + a0B + (wx0.x * xt.x + wx0.y * xt.y        \
                                        + wx0.z * xt.z + wx0.w * xt.w);      \
            const float A1 = a1A + a1B + (wx1.x * xt.x + wx1.y * xt.y        \
                                        + wx1.z * xt.z + wx1.w * xt.w);      \
            float s0, s1;                                                    \
            if (w == 0) { s0 = fast_sigmoid(A0); s1 = fast_sigmoid(A1); }    \
            else        { s0 = fast_tanh(A0);    s1 = fast_sigmoid(A1); }    \
            gbuf[P][w][l] = make_float2(s0, s1);                             \
            __syncthreads();                                                 \
            const float2 ov = gbuf[P][w ^ 1][l];                             \
            float gi, gf, gg, go;                                            \
            if (w == 0) { gi = s0; gf = s1; gg = ov.x; go = ov.y; }          \
            else        { gi = ov.x; gf = ov.y; gg = s0; go = s1; }          \
            c = gf * c + gi * gg;                                            \
            h = go * fast_tanh(c);                                           \
            const unsigned hr = __builtin_bit_cast(unsigned,                 \
                                    __builtin_amdgcn_cvt_pkrtz(h, h));       \
            const unsigned nb = (unsigned)__builtin_amdgcn_update_dpp(       \
                                    (int)hr, (int)hr, 0xB1, 0xF, 0xF, true); \
            const unsigned pk = (hr & 0xffffu) | (nb << 16);                 \
            _Pragma("unroll")                                                \
            for (int k = 0; k < 32; ++k)                                     \
                hs[k] = (unsigned)__builtin_amdgcn_readlane((int)pk, 2 * k); \
        } while (0)

        for (int s = 0; s < nst; s += 2) {
            STEP(s,     0);
            STEP(s + 1, 1);
        }
        #undef STEP

        if (more) {
            xstage[(ch + 1) & 1][tid]       = xn0;
            xstage[(ch + 1) & 1][tid + 128] = xn1;
            __syncthreads();
        }
    }

    #undef W2
    #undef H2
    #undef PIN_WU

    // ---- epilogue: wave 0 — backward cell + fc + sigmoid ----
    if (w == 0) {
        // backward-direction single cell from zero state at x[:, T-1]
        // (w_hh_b never multiplies nonzero state)
        float4 xl = *(const float4*)(xb + 4 * (T - 1));
        float gb[4];
        #pragma unroll
        for (int g = 0; g < 4; ++g) {
            const int r = (g << 6) | l;
            float4 wb = *(const float4*)(w_ih_b + (size_t)r * 4);
            gb[g] = b_ih_b[r] + b_hh_b[r]
                  + wb.x * xl.x + wb.y * xl.y + wb.z * xl.z + wb.w * xl.w;
        }
        const float ib  = fast_sigmoid(gb[0]);
        const float ggb = fast_tanh(gb[2]);
        const float ob  = fast_sigmoid(gb[3]);
        const float cb  = ib * ggb;
        const float hbk = ob * fast_tanh(cb);

        // h register holds the final forward h for unit l (computed redundantly)
        float p = w_fc[l] * h + w_fc[HDIM + l] * hbk;
        #pragma unroll
        for (int off = 32; off; off >>= 1) p += __shfl_xor(p, off);

        if (l == 0) out[b] = fast_sigmoid(p + b_fc[0]);
    }
}

extern "C" void kernel_launch(void* const* d_in, const int* in_sizes, int n_in,
                              void* d_out, int out_size, void* d_ws, size_t ws_size,
                              hipStream_t stream) {
    const float* x      = (const float*)d_in[0];
    const float* w_ih_f = (const float*)d_in[1];
    const float* w_hh_f = (const float*)d_in[2];
    const float* b_ih_f = (const float*)d_in[3];
    const float* b_hh_f = (const float*)d_in[4];
    const float* w_ih_b = (const float*)d_in[5];
    // d_in[6] = w_hh_b — unused (backward cell starts from zero state)
    const float* b_ih_b = (const float*)d_in[7];
    const float* b_hh_b = (const float*)d_in[8];
    const float* w_fc   = (const float*)d_in[9];
    const float* b_fc   = (const float*)d_in[10];
    float* out = (float*)d_out;

    const int B = out_size;                 // 512
    const int T = in_sizes[0] / (B * 4);    // 1000

    bilstm_kernel<<<dim3(B), dim3(128), 0, stream>>>(
        x, w_ih_f, w_hh_f, b_ih_f, b_hh_f,
        w_ih_b, b_ih_b, b_hh_b, w_fc, b_fc, out, T);
}